// Round 5
// baseline (489.019 us; speedup 1.0000x reference)
//
#include <hip/hip_runtime.h>
#include <hip/hip_bf16.h>
#include <math.h>

#define NN 16384       // nodes
#define EE 131072      // edges
#define FIN 16
#define HID 128
#define NEG_SLOPE 0.2f

// ---------------------------------------------------------------------------
// CSR build
// ---------------------------------------------------------------------------
__global__ void count_kernel(const int* __restrict__ dst, int* __restrict__ deg) {
    int e = blockIdx.x * 256 + threadIdx.x;
    atomicAdd(&deg[dst[e]], 1);
}

__global__ __launch_bounds__(1024) void scan_kernel(int* __restrict__ degw /* in: deg, out: offsets */,
                                                    int* __restrict__ ptr) {
    __shared__ int sums[1024];
    int t = threadIdx.x;
    int base = t * 16;
    int local[16];
    int s = 0;
#pragma unroll
    for (int i = 0; i < 16; i++) { local[i] = degw[base + i]; s += local[i]; }
    sums[t] = s;
    __syncthreads();
    for (int off = 1; off < 1024; off <<= 1) {
        int v = (t >= off) ? sums[t - off] : 0;
        __syncthreads();
        sums[t] += v;
        __syncthreads();
    }
    int ex = (t == 0) ? 0 : sums[t - 1];
#pragma unroll
    for (int i = 0; i < 16; i++) {
        ptr[base + i] = ex;
        degw[base + i] = ex;   // working copy for scatter
        ex += local[i];
    }
    if (t == 1023) ptr[NN] = sums[1023];
}

__global__ void scatter_kernel(const int* __restrict__ src, const int* __restrict__ dst,
                               int* __restrict__ ptrw, int* __restrict__ csr_src) {
    int e = blockIdx.x * 256 + threadIdx.x;
    int p = atomicAdd(&ptrw[dst[e]], 1);
    csr_src[p] = src[e];
}

// ---------------------------------------------------------------------------
// Layer 0 linear for a pass of views: local row lw -> abs view = viewBase + lw>>14
// ---------------------------------------------------------------------------
__global__ __launch_bounds__(256) void l0_kernel(const float* __restrict__ x,
                                                 const float* __restrict__ W0l,
                                                 const float* __restrict__ W0r,
                                                 const float* __restrict__ Wres,
                                                 float* __restrict__ hl,
                                                 float* __restrict__ hr,
                                                 float* __restrict__ hres,
                                                 int viewBase) {
    __shared__ float wl[FIN * HID], wr[FIN * HID], ws[FIN * HID];
    int tid = threadIdx.x;
#pragma unroll
    for (int i = 0; i < 8; i++) {
        int idx = tid + i * 256;
        wl[idx] = W0l[idx];
        wr[idx] = W0r[idx];
        ws[idx] = Wres[idx];
    }
    __syncthreads();
    long lw = (long)blockIdx.x * 2 + (tid >> 7);   // local row in pass
    int col = tid & 127;
    int v = viewBase + (int)(lw >> 14);            // absolute view
    int n = (int)(lw & (NN - 1));                  // node
    float al = 0.f, ar = 0.f, as_ = 0.f;
#pragma unroll
    for (int k = 0; k < FIN; k++) {
        float xk = x[n * FIN + k];
        if (k == 0 && (v & 1)) xk = -xk;   // flip x for views 1,3
        if (k == 1 && (v & 2)) xk = -xk;   // flip y for views 2,3
        al += xk * wl[k * HID + col];
        ar += xk * wr[k * HID + col];
        as_ += xk * ws[k * HID + col];
    }
    hl[lw * HID + col] = al;
    hr[lw * HID + col] = ar;
    hres[lw * HID + col] = as_;
}

// ---------------------------------------------------------------------------
// GATv2 edge attention + aggregate + residual + (optional) ELU.
// One wave per local row, XCD-swizzled so all 256 blocks of one (graph,view)
// land on ONE XCD (dispatch round-robins blockIdx across 8 XCDs): the
// 512 KB hl working set of that graph-view stays L2-resident instead of
// being refetched from L3 by all 8 XCDs. Pure work permutation — output
// is bit-identical to the linear mapping.
// Lane layout: head = l>>4, dim pair = (l&15)*2. Online softmax over
// incoming edges (CSR by dst), 2-edge unrolled to halve the serial chain.
// hout may alias hr or res (each wave reads hr/res only at its own row).
// ---------------------------------------------------------------------------
__global__ __launch_bounds__(256) void attn_kernel(const float* __restrict__ hl,
                                                   const float* __restrict__ hr,
                                                   const float* __restrict__ res,
                                                   const int* __restrict__ ptr,
                                                   const int* __restrict__ csr_src,
                                                   const float* __restrict__ avec,
                                                   float* __restrict__ hout,
                                                   int act,
                                                   int gvPerXcd) {
    // blockIdx.x in [0, GV*256): 256 blocks (1024 rows) per graph-view chunk.
    int xcd = blockIdx.x & 7;
    int slot = blockIdx.x >> 3;                      // [0, GV*32)
    int gv = xcd * gvPerXcd + (slot >> 8);           // graph-view chunk id
    int within = slot & 255;                         // block within chunk
    int gw = (gv << 10) + (within << 2) + (threadIdx.x >> 6);  // local row
    int l = threadIdx.x & 63;
    int n = gw & (NN - 1);
    int col = ((l >> 4) << 5) + ((l & 15) << 1);     // head*32 + pair*2
    long base = (long)gw * HID;
    float2 hr2 = *(const float2*)(hr + base + col);
    float2 a2 = *(const float2*)(avec + col);
    float m = -INFINITY, ssum = 0.f, acc0 = 0.f, acc1 = 0.f;
    int beg = ptr[n], end = ptr[n + 1];
    long vbase = (long)(gw >> 14) * NN * HID;        // view base within pass
    int j = beg;
    for (; j + 1 < end; j += 2) {
        int sa = csr_src[j];
        int sb = csr_src[j + 1];
        float2 ha = *(const float2*)(hl + vbase + (long)sa * HID + col);
        float2 hb = *(const float2*)(hl + vbase + (long)sb * HID + col);
        float sa0 = ha.x + hr2.x, sa1 = ha.y + hr2.y;
        float sb0 = hb.x + hr2.x, sb1 = hb.y + hr2.y;
        float ta0 = sa0 > 0.f ? sa0 : NEG_SLOPE * sa0;
        float ta1 = sa1 > 0.f ? sa1 : NEG_SLOPE * sa1;
        float tb0 = sb0 > 0.f ? sb0 : NEG_SLOPE * sb0;
        float tb1 = sb1 > 0.f ? sb1 : NEG_SLOPE * sb1;
        float p1 = ta0 * a2.x + ta1 * a2.y;
        float p2 = tb0 * a2.x + tb1 * a2.y;
        p1 += __shfl_xor(p1, 1, 16);
        p2 += __shfl_xor(p2, 1, 16);
        p1 += __shfl_xor(p1, 2, 16);
        p2 += __shfl_xor(p2, 2, 16);
        p1 += __shfl_xor(p1, 4, 16);
        p2 += __shfl_xor(p2, 4, 16);
        p1 += __shfl_xor(p1, 8, 16);
        p2 += __shfl_xor(p2, 8, 16);
        // pairwise merge, then merge into running state
        float m12 = fmaxf(p1, p2);
        float w1 = __expf(p1 - m12);
        float w2 = __expf(p2 - m12);
        float mn = fmaxf(m, m12);
        float cold = __expf(m - mn);    // first iter: exp(-inf)=0
        float c12 = __expf(m12 - mn);
        ssum = ssum * cold + (w1 + w2) * c12;
        acc0 = acc0 * cold + (w1 * ha.x + w2 * hb.x) * c12;
        acc1 = acc1 * cold + (w1 * ha.y + w2 * hb.y) * c12;
        m = mn;
    }
    if (j < end) {
        int sa = csr_src[j];
        float2 ha = *(const float2*)(hl + vbase + (long)sa * HID + col);
        float s0 = ha.x + hr2.x, s1 = ha.y + hr2.y;
        float t0 = s0 > 0.f ? s0 : NEG_SLOPE * s0;
        float t1 = s1 > 0.f ? s1 : NEG_SLOPE * s1;
        float p = t0 * a2.x + t1 * a2.y;
        p += __shfl_xor(p, 1, 16);
        p += __shfl_xor(p, 2, 16);
        p += __shfl_xor(p, 4, 16);
        p += __shfl_xor(p, 8, 16);
        float mn = fmaxf(m, p);
        float cold = __expf(m - mn);
        float wnew = __expf(p - mn);
        ssum = ssum * cold + wnew;
        acc0 = acc0 * cold + wnew * ha.x;
        acc1 = acc1 * cold + wnew * ha.y;
        m = mn;
    }
    float inv = 1.f / (ssum + 1e-16f);   // deg==0 -> acc=0 -> out = res (matches ref)
    float2 r2 = *(const float2*)(res + base + col);
    float o0 = acc0 * inv + r2.x;
    float o1 = acc1 * inv + r2.y;
    if (act) {
        o0 = o0 > 0.f ? o0 : expm1f(o0);
        o1 = o1 > 0.f ? o1 : expm1f(o1);
    }
    *(float2*)(hout + base + col) = make_float2(o0, o1);
}

// ---------------------------------------------------------------------------
// fp32 GEMM: C[M][128] = A[M][128] @ B[128][128]  (+optional bias/ReLU)
// Block tile 128x128 (256 threads), per-thread 8x8:
//   rows  ty + 16*r  (r=0..7)  -> wave's 4 A-addresses hit banks {b,b+4,b+8,b+12}
//   cols {tx*4, 64+tx*4}       -> wave's 16 B-addresses, 2 per bank-quad (free)
// K staged in chunks of 32; LDS ~35 KB. 1.0 B LDS traffic per lane-FMA.
// blockIdx.z selects (B0,C0) or (B1,C1).
// ---------------------------------------------------------------------------
#define KC 32
__global__ __launch_bounds__(256) void gemm128(const float* __restrict__ A,
                                               const float* __restrict__ B0,
                                               const float* __restrict__ B1,
                                               float* __restrict__ C0,
                                               float* __restrict__ C1,
                                               const float* __restrict__ bias,
                                               int doRelu) {
    const float* B = (blockIdx.z == 0) ? B0 : B1;
    float* C = (blockIdx.z == 0) ? C0 : C1;
    __shared__ float As[128][36];   // stride 36: +1 row -> +4 banks, 16B-aligned rows
    __shared__ float Bs[KC][132];   // stride 132: +1 k -> +4 banks, 16B-aligned rows
    int tid = threadIdx.x;
    int tx = tid & 15;
    int ty = tid >> 4;
    long row0 = (long)blockIdx.x * 128;
    float acc[8][8];
#pragma unroll
    for (int r = 0; r < 8; r++)
#pragma unroll
        for (int j = 0; j < 8; j++) acc[r][j] = 0.f;

    for (int kc = 0; kc < HID; kc += KC) {
        // stage A: 128 rows x 32 k  (1024 float4, 4 per thread)
#pragma unroll
        for (int i = 0; i < 4; i++) {
            int idx = tid + i * 256;
            int r = idx >> 3;
            int k4 = (idx & 7) * 4;
            float4 vv = *(const float4*)(A + (row0 + r) * HID + kc + k4);
            *(float4*)(&As[r][k4]) = vv;
        }
        // stage B: 32 k x 128 cols  (1024 float4, 4 per thread)
#pragma unroll
        for (int i = 0; i < 4; i++) {
            int idx = tid + i * 256;
            int kk = idx >> 5;
            int c4 = (idx & 31) * 4;
            float4 vv = *(const float4*)(B + (kc + kk) * HID + c4);
            *(float4*)(&Bs[kk][c4]) = vv;
        }
        __syncthreads();
#pragma unroll
        for (int k4 = 0; k4 < KC; k4 += 4) {
            float4 a[8];
            float4 b[4][2];
#pragma unroll
            for (int r = 0; r < 8; r++) a[r] = *(const float4*)(&As[ty + 16 * r][k4]);
#pragma unroll
            for (int kk = 0; kk < 4; kk++) {
                b[kk][0] = *(const float4*)(&Bs[k4 + kk][tx * 4]);
                b[kk][1] = *(const float4*)(&Bs[k4 + kk][64 + tx * 4]);
            }
#pragma unroll
            for (int kk = 0; kk < 4; kk++) {
#pragma unroll
                for (int r = 0; r < 8; r++) {
                    float av = reinterpret_cast<const float*>(&a[r])[kk];
                    acc[r][0] += av * b[kk][0].x;
                    acc[r][1] += av * b[kk][0].y;
                    acc[r][2] += av * b[kk][0].z;
                    acc[r][3] += av * b[kk][0].w;
                    acc[r][4] += av * b[kk][1].x;
                    acc[r][5] += av * b[kk][1].y;
                    acc[r][6] += av * b[kk][1].z;
                    acc[r][7] += av * b[kk][1].w;
                }
            }
        }
        __syncthreads();
    }
#pragma unroll
    for (int r = 0; r < 8; r++) {
        long row = row0 + ty + 16 * r;
        float o[8];
#pragma unroll
        for (int j = 0; j < 4; j++) {
            float val = acc[r][j];
            if (bias) val += bias[tx * 4 + j];
            if (doRelu) val = fmaxf(val, 0.f);
            o[j] = val;
        }
#pragma unroll
        for (int j = 4; j < 8; j++) {
            float val = acc[r][j];
            if (bias) val += bias[64 + tx * 4 + (j - 4)];
            if (doRelu) val = fmaxf(val, 0.f);
            o[j] = val;
        }
        float* crow = C + row * HID + tx * 4;
        *(float4*)crow = make_float4(o[0], o[1], o[2], o[3]);
        *(float4*)(crow + 64) = make_float4(o[4], o[5], o[6], o[7]);
    }
}

// ---------------------------------------------------------------------------
// Accumulate 0.25 * sum over the pass's k views into emb  (emb pre-zeroed)
// ---------------------------------------------------------------------------
__global__ void acc_kernel(const float* __restrict__ h, float* __restrict__ emb, int k) {
    int i = blockIdx.x * 256 + threadIdx.x;  // over NN*32 float4s
    const float4* h4 = (const float4*)h;
    float4 s = make_float4(0.f, 0.f, 0.f, 0.f);
    for (int lv = 0; lv < k; lv++) {
        float4 a = h4[i + (long)lv * NN * 32];
        s.x += a.x; s.y += a.y; s.z += a.z; s.w += a.w;
    }
    float4* e4 = (float4*)emb;
    float4 o = e4[i];
    o.x += 0.25f * s.x; o.y += 0.25f * s.y; o.z += 0.25f * s.z; o.w += 0.25f * s.w;
    e4[i] = o;
}

// ---------------------------------------------------------------------------
// Final logits: out[n] = z[n][:] . Wh2 + bh2   (one wave per node)
// ---------------------------------------------------------------------------
__global__ void logits_kernel(const float* __restrict__ z, const float* __restrict__ Wh2,
                              const float* __restrict__ bh2, float* __restrict__ out) {
    int w = (blockIdx.x * 256 + threadIdx.x) >> 6;
    int l = threadIdx.x & 63;
    float v = z[(long)w * HID + l] * Wh2[l] + z[(long)w * HID + 64 + l] * Wh2[64 + l];
    v += __shfl_xor(v, 32);
    v += __shfl_xor(v, 16);
    v += __shfl_xor(v, 8);
    v += __shfl_xor(v, 4);
    v += __shfl_xor(v, 2);
    v += __shfl_xor(v, 1);
    if (l == 0) out[w] = v + bh2[0];
}

// ---------------------------------------------------------------------------
extern "C" void kernel_launch(void* const* d_in, const int* in_sizes, int n_in,
                              void* d_out, int out_size, void* d_ws, size_t ws_size,
                              hipStream_t stream) {
    const float* x    = (const float*)d_in[0];
    const int*   ei   = (const int*)d_in[1];      // [2][E]: src then dst
    const float* W0l  = (const float*)d_in[3];
    const float* W0r  = (const float*)d_in[4];
    const float* a0   = (const float*)d_in[5];
    const float* Wres0= (const float*)d_in[6];
    const float* Wl   = (const float*)d_in[7];    // [2][128][128]
    const float* Wr   = (const float*)d_in[8];
    const float* att  = (const float*)d_in[9];    // [2][4][32]
    const float* Wh1  = (const float*)d_in[10];
    const float* bh1  = (const float*)d_in[11];
    const float* Wh2  = (const float*)d_in[12];
    const float* bh2  = (const float*)d_in[13];
    float* out = (float*)d_out;

    const int* src = ei;
    const int* dst = ei + EE;

    // workspace layout: emb | ptr | ptrw | csr | (256B-aligned) bufA | bufB | bufC
    char* wsb = (char*)d_ws;
    float* emb = (float*)wsb;                               // [NN][128]
    size_t off = (size_t)NN * HID * 4;
    int* ptr  = (int*)(wsb + off);  off += (NN + 1) * 4;    // [NN+1]
    int* ptrw = (int*)(wsb + off);  off += NN * 4;          // [NN]
    int* csr  = (int*)(wsb + off);  off += (size_t)EE * 4;  // [EE]
    off = (off + 255) & ~(size_t)255;                       // alignment for float4
    size_t fixedBytes = off;

    // ws-adaptive pass sizing: k views per pass, k in {4,2,1}
    int k = 4;
    while (k > 1 && fixedBytes + 3ull * k * NN * HID * 4 > ws_size) k >>= 1;
    long K = (long)k * NN;           // rows per pass
    int npass = 4 / k;
    int gvPerXcd = (int)(K / 1024) / 8;   // graph-view chunks per XCD (k=1 -> 2)

    float* bufA = (float*)(wsb + off);            // [K][128]
    float* bufB = bufA + K * HID;                 // [K][128]
    float* bufC = bufB + K * HID;                 // [K][128]

    // --- CSR build (shared by all views/layers) ---
    hipMemsetAsync(ptrw, 0, NN * sizeof(int), stream);
    count_kernel<<<EE / 256, 256, 0, stream>>>(dst, ptrw);
    scan_kernel<<<1, 1024, 0, stream>>>(ptrw, ptr);
    scatter_kernel<<<EE / 256, 256, 0, stream>>>(src, dst, ptrw, csr);

    // --- emb = 0 ---
    hipMemsetAsync(emb, 0, (size_t)NN * HID * sizeof(float), stream);

    for (int p = 0; p < npass; p++) {
        int viewBase = p * k;
        // layer 0: hl->A, hr->B, hres->C;  attn0 (res=C) -> B (h0)
        l0_kernel<<<K / 2, 256, 0, stream>>>(x, W0l, W0r, Wres0, bufA, bufB, bufC, viewBase);
        attn_kernel<<<K / 4, 256, 0, stream>>>(bufA, bufB, bufC, ptr, csr, a0, bufB, 1, gvPerXcd);
        // layer 1: gemm B->(A=hl, C=hr);  attn1 (res=B) -> C (h1)
        gemm128<<<dim3(K / 128, 1, 2), 256, 0, stream>>>(bufB, Wl, Wr, bufA, bufC, nullptr, 0);
        attn_kernel<<<K / 4, 256, 0, stream>>>(bufA, bufC, bufB, ptr, csr, att, bufC, 1, gvPerXcd);
        // layer 2: gemm C->(A=hl, B=hr);  attn2 (res=C, no act) -> B (h2)
        gemm128<<<dim3(K / 128, 1, 2), 256, 0, stream>>>(bufC, Wl + HID * HID, Wr + HID * HID,
                                                         bufA, bufB, nullptr, 0);
        attn_kernel<<<K / 4, 256, 0, stream>>>(bufA, bufB, bufC, ptr, csr, att + HID, bufB, 0, gvPerXcd);
        // accumulate mean over views
        acc_kernel<<<NN * 32 / 256, 256, 0, stream>>>(bufB, emb, k);
    }

    // --- head: z = relu(emb@Wh1+bh1) -> bufA;  logits(bufA) -> out ---
    gemm128<<<dim3(NN / 128, 1, 1), 256, 0, stream>>>(emb, Wh1, Wh1, bufA, bufA, bh1, 1);
    logits_kernel<<<NN * 64 / 256, 256, 0, stream>>>(bufA, Wh2, bh2, out);
}

// Round 6
// 438.366 us; speedup vs baseline: 1.1156x; 1.1156x over previous
//
#include <hip/hip_runtime.h>
#include <hip/hip_bf16.h>
#include <math.h>

#define NN 16384       // nodes
#define EE 131072      // edges
#define FIN 16
#define HID 128
#define NEG_SLOPE 0.2f

// ---------------------------------------------------------------------------
// CSR build
// ---------------------------------------------------------------------------
__global__ void count_kernel(const int* __restrict__ dst, int* __restrict__ deg) {
    int e = blockIdx.x * 256 + threadIdx.x;
    atomicAdd(&deg[dst[e]], 1);
}

__global__ __launch_bounds__(1024) void scan_kernel(int* __restrict__ degw /* in: deg, out: offsets */,
                                                    int* __restrict__ ptr) {
    __shared__ int sums[1024];
    int t = threadIdx.x;
    int base = t * 16;
    int local[16];
    int s = 0;
#pragma unroll
    for (int i = 0; i < 16; i++) { local[i] = degw[base + i]; s += local[i]; }
    sums[t] = s;
    __syncthreads();
    for (int off = 1; off < 1024; off <<= 1) {
        int v = (t >= off) ? sums[t - off] : 0;
        __syncthreads();
        sums[t] += v;
        __syncthreads();
    }
    int ex = (t == 0) ? 0 : sums[t - 1];
#pragma unroll
    for (int i = 0; i < 16; i++) {
        ptr[base + i] = ex;
        degw[base + i] = ex;   // working copy for scatter
        ex += local[i];
    }
    if (t == 1023) ptr[NN] = sums[1023];
}

__global__ void scatter_kernel(const int* __restrict__ src, const int* __restrict__ dst,
                               int* __restrict__ ptrw, int* __restrict__ csr_src) {
    int e = blockIdx.x * 256 + threadIdx.x;
    int p = atomicAdd(&ptrw[dst[e]], 1);
    csr_src[p] = src[e];
}

// ---------------------------------------------------------------------------
// Layer 0 linear, persistent grid-stride version.
// r5 counters showed the old per-block LDS staging (32768 blocks x 24KB =
// 768MB L2 traffic) bound the kernel at 80us / 1.26 TB/s. Now: 2048 blocks,
// each THREAD owns 2 output columns and keeps its 3x16 float2 weight slice
// in registers (loaded once, 75MB L2 total), then grid-strides over rows.
// Rows per iter: 4 (tid>>6); x-row reads are wave-uniform; float2 stores.
// ---------------------------------------------------------------------------
#define L0_BLOCKS 2048
__global__ __launch_bounds__(256) void l0_kernel(const float* __restrict__ x,
                                                 const float* __restrict__ W0l,
                                                 const float* __restrict__ W0r,
                                                 const float* __restrict__ Wres,
                                                 float* __restrict__ hl,
                                                 float* __restrict__ hr,
                                                 float* __restrict__ hres,
                                                 int viewBase, long totalRows) {
    int tid = threadIdx.x;
    int c2 = (tid & 63) * 2;
    float2 wl2[FIN], wr2[FIN], ws2[FIN];
#pragma unroll
    for (int k = 0; k < FIN; k++) {
        wl2[k] = *(const float2*)(W0l + k * HID + c2);
        wr2[k] = *(const float2*)(W0r + k * HID + c2);
        ws2[k] = *(const float2*)(Wres + k * HID + c2);
    }
    for (long lw = (long)blockIdx.x * 4 + (tid >> 6); lw < totalRows;
         lw += (long)L0_BLOCKS * 4) {
        int v = viewBase + (int)(lw >> 14);            // absolute view
        int n = (int)(lw & (NN - 1));                  // node
        const float* xr = x + (long)n * FIN;
        float al0 = 0.f, al1 = 0.f, ar0 = 0.f, ar1 = 0.f, as0 = 0.f, as1 = 0.f;
#pragma unroll
        for (int k = 0; k < FIN; k++) {
            float xk = xr[k];                          // wave-uniform
            if (k == 0 && (v & 1)) xk = -xk;           // flip x for views 1,3
            if (k == 1 && (v & 2)) xk = -xk;           // flip y for views 2,3
            al0 += xk * wl2[k].x; al1 += xk * wl2[k].y;
            ar0 += xk * wr2[k].x; ar1 += xk * wr2[k].y;
            as0 += xk * ws2[k].x; as1 += xk * ws2[k].y;
        }
        long base = lw * HID + c2;
        *(float2*)(hl + base)   = make_float2(al0, al1);
        *(float2*)(hr + base)   = make_float2(ar0, ar1);
        *(float2*)(hres + base) = make_float2(as0, as1);
    }
}

// ---------------------------------------------------------------------------
// GATv2 edge attention + aggregate + residual + (optional) ELU.
// One wave per local row, XCD-swizzled so all 256 blocks of one (graph,view)
// land on ONE XCD (dispatch round-robins blockIdx across 8 XCDs): the
// 512 KB hl working set of that graph-view stays L2-resident. Pure work
// permutation — output bit-identical to the linear mapping.
// Lane layout: head = l>>4, dim pair = (l&15)*2. Online softmax over
// incoming edges (CSR by dst), 2-edge unrolled to halve the serial chain.
// hout may alias hr or res (each wave reads hr/res only at its own row).
// ---------------------------------------------------------------------------
__global__ __launch_bounds__(256) void attn_kernel(const float* __restrict__ hl,
                                                   const float* __restrict__ hr,
                                                   const float* __restrict__ res,
                                                   const int* __restrict__ ptr,
                                                   const int* __restrict__ csr_src,
                                                   const float* __restrict__ avec,
                                                   float* __restrict__ hout,
                                                   int act,
                                                   int gvPerXcd) {
    // blockIdx.x in [0, GV*256): 256 blocks (1024 rows) per graph-view chunk.
    int xcd = blockIdx.x & 7;
    int slot = blockIdx.x >> 3;                      // [0, GV*32)
    int gv = xcd * gvPerXcd + (slot >> 8);           // graph-view chunk id
    int within = slot & 255;                         // block within chunk
    int gw = (gv << 10) + (within << 2) + (threadIdx.x >> 6);  // local row
    int l = threadIdx.x & 63;
    int n = gw & (NN - 1);
    int col = ((l >> 4) << 5) + ((l & 15) << 1);     // head*32 + pair*2
    long base = (long)gw * HID;
    float2 hr2 = *(const float2*)(hr + base + col);
    float2 a2 = *(const float2*)(avec + col);
    float m = -INFINITY, ssum = 0.f, acc0 = 0.f, acc1 = 0.f;
    int beg = ptr[n], end = ptr[n + 1];
    long vbase = (long)(gw >> 14) * NN * HID;        // view base within pass
    int j = beg;
    for (; j + 1 < end; j += 2) {
        int sa = csr_src[j];
        int sb = csr_src[j + 1];
        float2 ha = *(const float2*)(hl + vbase + (long)sa * HID + col);
        float2 hb = *(const float2*)(hl + vbase + (long)sb * HID + col);
        float sa0 = ha.x + hr2.x, sa1 = ha.y + hr2.y;
        float sb0 = hb.x + hr2.x, sb1 = hb.y + hr2.y;
        float ta0 = sa0 > 0.f ? sa0 : NEG_SLOPE * sa0;
        float ta1 = sa1 > 0.f ? sa1 : NEG_SLOPE * sa1;
        float tb0 = sb0 > 0.f ? sb0 : NEG_SLOPE * sb0;
        float tb1 = sb1 > 0.f ? sb1 : NEG_SLOPE * sb1;
        float p1 = ta0 * a2.x + ta1 * a2.y;
        float p2 = tb0 * a2.x + tb1 * a2.y;
        p1 += __shfl_xor(p1, 1, 16);
        p2 += __shfl_xor(p2, 1, 16);
        p1 += __shfl_xor(p1, 2, 16);
        p2 += __shfl_xor(p2, 2, 16);
        p1 += __shfl_xor(p1, 4, 16);
        p2 += __shfl_xor(p2, 4, 16);
        p1 += __shfl_xor(p1, 8, 16);
        p2 += __shfl_xor(p2, 8, 16);
        // pairwise merge, then merge into running state
        float m12 = fmaxf(p1, p2);
        float w1 = __expf(p1 - m12);
        float w2 = __expf(p2 - m12);
        float mn = fmaxf(m, m12);
        float cold = __expf(m - mn);    // first iter: exp(-inf)=0
        float c12 = __expf(m12 - mn);
        ssum = ssum * cold + (w1 + w2) * c12;
        acc0 = acc0 * cold + (w1 * ha.x + w2 * hb.x) * c12;
        acc1 = acc1 * cold + (w1 * ha.y + w2 * hb.y) * c12;
        m = mn;
    }
    if (j < end) {
        int sa = csr_src[j];
        float2 ha = *(const float2*)(hl + vbase + (long)sa * HID + col);
        float s0 = ha.x + hr2.x, s1 = ha.y + hr2.y;
        float t0 = s0 > 0.f ? s0 : NEG_SLOPE * s0;
        float t1 = s1 > 0.f ? s1 : NEG_SLOPE * s1;
        float p = t0 * a2.x + t1 * a2.y;
        p += __shfl_xor(p, 1, 16);
        p += __shfl_xor(p, 2, 16);
        p += __shfl_xor(p, 4, 16);
        p += __shfl_xor(p, 8, 16);
        float mn = fmaxf(m, p);
        float cold = __expf(m - mn);
        float wnew = __expf(p - mn);
        ssum = ssum * cold + wnew;
        acc0 = acc0 * cold + wnew * ha.x;
        acc1 = acc1 * cold + wnew * ha.y;
        m = mn;
    }
    float inv = 1.f / (ssum + 1e-16f);   // deg==0 -> acc=0 -> out = res (matches ref)
    float2 r2 = *(const float2*)(res + base + col);
    float o0 = acc0 * inv + r2.x;
    float o1 = acc1 * inv + r2.y;
    if (act) {
        o0 = o0 > 0.f ? o0 : expm1f(o0);
        o1 = o1 > 0.f ? o1 : expm1f(o1);
    }
    *(float2*)(hout + base + col) = make_float2(o0, o1);
}

// ---------------------------------------------------------------------------
// fp32 GEMM: C[M][128] = A[M][128] @ B[128][128]  (+optional bias/ReLU)
// Block tile 128x128 (256 threads), per-thread 8x8:
//   rows  ty + 16*r  (r=0..7)  -> wave's 4 A-addresses hit banks {b,b+4,b+8,b+12}
//   cols {tx*4, 64+tx*4}       -> wave's 16 B-addresses, 2 per bank-quad (free)
// K staged in chunks of 32; LDS ~35 KB. 1.0 B LDS traffic per lane-FMA.
// blockIdx.z selects (B0,C0) or (B1,C1).
// ---------------------------------------------------------------------------
#define KC 32
__global__ __launch_bounds__(256) void gemm128(const float* __restrict__ A,
                                               const float* __restrict__ B0,
                                               const float* __restrict__ B1,
                                               float* __restrict__ C0,
                                               float* __restrict__ C1,
                                               const float* __restrict__ bias,
                                               int doRelu) {
    const float* B = (blockIdx.z == 0) ? B0 : B1;
    float* C = (blockIdx.z == 0) ? C0 : C1;
    __shared__ float As[128][36];   // stride 36: +1 row -> +4 banks, 16B-aligned rows
    __shared__ float Bs[KC][132];   // stride 132: +1 k -> +4 banks, 16B-aligned rows
    int tid = threadIdx.x;
    int tx = tid & 15;
    int ty = tid >> 4;
    long row0 = (long)blockIdx.x * 128;
    float acc[8][8];
#pragma unroll
    for (int r = 0; r < 8; r++)
#pragma unroll
        for (int j = 0; j < 8; j++) acc[r][j] = 0.f;

    for (int kc = 0; kc < HID; kc += KC) {
        // stage A: 128 rows x 32 k  (1024 float4, 4 per thread)
#pragma unroll
        for (int i = 0; i < 4; i++) {
            int idx = tid + i * 256;
            int r = idx >> 3;
            int k4 = (idx & 7) * 4;
            float4 vv = *(const float4*)(A + (row0 + r) * HID + kc + k4);
            *(float4*)(&As[r][k4]) = vv;
        }
        // stage B: 32 k x 128 cols  (1024 float4, 4 per thread)
#pragma unroll
        for (int i = 0; i < 4; i++) {
            int idx = tid + i * 256;
            int kk = idx >> 5;
            int c4 = (idx & 31) * 4;
            float4 vv = *(const float4*)(B + (kc + kk) * HID + c4);
            *(float4*)(&Bs[kk][c4]) = vv;
        }
        __syncthreads();
#pragma unroll
        for (int k4 = 0; k4 < KC; k4 += 4) {
            float4 a[8];
            float4 b[4][2];
#pragma unroll
            for (int r = 0; r < 8; r++) a[r] = *(const float4*)(&As[ty + 16 * r][k4]);
#pragma unroll
            for (int kk = 0; kk < 4; kk++) {
                b[kk][0] = *(const float4*)(&Bs[k4 + kk][tx * 4]);
                b[kk][1] = *(const float4*)(&Bs[k4 + kk][64 + tx * 4]);
            }
#pragma unroll
            for (int kk = 0; kk < 4; kk++) {
#pragma unroll
                for (int r = 0; r < 8; r++) {
                    float av = reinterpret_cast<const float*>(&a[r])[kk];
                    acc[r][0] += av * b[kk][0].x;
                    acc[r][1] += av * b[kk][0].y;
                    acc[r][2] += av * b[kk][0].z;
                    acc[r][3] += av * b[kk][0].w;
                    acc[r][4] += av * b[kk][1].x;
                    acc[r][5] += av * b[kk][1].y;
                    acc[r][6] += av * b[kk][1].z;
                    acc[r][7] += av * b[kk][1].w;
                }
            }
        }
        __syncthreads();
    }
#pragma unroll
    for (int r = 0; r < 8; r++) {
        long row = row0 + ty + 16 * r;
        float o[8];
#pragma unroll
        for (int j = 0; j < 4; j++) {
            float val = acc[r][j];
            if (bias) val += bias[tx * 4 + j];
            if (doRelu) val = fmaxf(val, 0.f);
            o[j] = val;
        }
#pragma unroll
        for (int j = 4; j < 8; j++) {
            float val = acc[r][j];
            if (bias) val += bias[64 + tx * 4 + (j - 4)];
            if (doRelu) val = fmaxf(val, 0.f);
            o[j] = val;
        }
        float* crow = C + row * HID + tx * 4;
        *(float4*)crow = make_float4(o[0], o[1], o[2], o[3]);
        *(float4*)(crow + 64) = make_float4(o[4], o[5], o[6], o[7]);
    }
}

// ---------------------------------------------------------------------------
// Accumulate 0.25 * sum over the pass's k views into emb  (emb pre-zeroed)
// ---------------------------------------------------------------------------
__global__ void acc_kernel(const float* __restrict__ h, float* __restrict__ emb, int k) {
    int i = blockIdx.x * 256 + threadIdx.x;  // over NN*32 float4s
    const float4* h4 = (const float4*)h;
    float4 s = make_float4(0.f, 0.f, 0.f, 0.f);
    for (int lv = 0; lv < k; lv++) {
        float4 a = h4[i + (long)lv * NN * 32];
        s.x += a.x; s.y += a.y; s.z += a.z; s.w += a.w;
    }
    float4* e4 = (float4*)emb;
    float4 o = e4[i];
    o.x += 0.25f * s.x; o.y += 0.25f * s.y; o.z += 0.25f * s.z; o.w += 0.25f * s.w;
    e4[i] = o;
}

// ---------------------------------------------------------------------------
// Final logits: out[n] = z[n][:] . Wh2 + bh2   (one wave per node)
// ---------------------------------------------------------------------------
__global__ void logits_kernel(const float* __restrict__ z, const float* __restrict__ Wh2,
                              const float* __restrict__ bh2, float* __restrict__ out) {
    int w = (blockIdx.x * 256 + threadIdx.x) >> 6;
    int l = threadIdx.x & 63;
    float v = z[(long)w * HID + l] * Wh2[l] + z[(long)w * HID + 64 + l] * Wh2[64 + l];
    v += __shfl_xor(v, 32);
    v += __shfl_xor(v, 16);
    v += __shfl_xor(v, 8);
    v += __shfl_xor(v, 4);
    v += __shfl_xor(v, 2);
    v += __shfl_xor(v, 1);
    if (l == 0) out[w] = v + bh2[0];
}

// ---------------------------------------------------------------------------
extern "C" void kernel_launch(void* const* d_in, const int* in_sizes, int n_in,
                              void* d_out, int out_size, void* d_ws, size_t ws_size,
                              hipStream_t stream) {
    const float* x    = (const float*)d_in[0];
    const int*   ei   = (const int*)d_in[1];      // [2][E]: src then dst
    const float* W0l  = (const float*)d_in[3];
    const float* W0r  = (const float*)d_in[4];
    const float* a0   = (const float*)d_in[5];
    const float* Wres0= (const float*)d_in[6];
    const float* Wl   = (const float*)d_in[7];    // [2][128][128]
    const float* Wr   = (const float*)d_in[8];
    const float* att  = (const float*)d_in[9];    // [2][4][32]
    const float* Wh1  = (const float*)d_in[10];
    const float* bh1  = (const float*)d_in[11];
    const float* Wh2  = (const float*)d_in[12];
    const float* bh2  = (const float*)d_in[13];
    float* out = (float*)d_out;

    const int* src = ei;
    const int* dst = ei + EE;

    // workspace layout: emb | ptr | ptrw | csr | (256B-aligned) bufA | bufB | bufC
    char* wsb = (char*)d_ws;
    float* emb = (float*)wsb;                               // [NN][128]
    size_t off = (size_t)NN * HID * 4;
    int* ptr  = (int*)(wsb + off);  off += (NN + 1) * 4;    // [NN+1]
    int* ptrw = (int*)(wsb + off);  off += NN * 4;          // [NN]
    int* csr  = (int*)(wsb + off);  off += (size_t)EE * 4;  // [EE]
    off = (off + 255) & ~(size_t)255;                       // alignment for float4
    size_t fixedBytes = off;

    // ws-adaptive pass sizing: k views per pass, k in {4,2,1}
    int k = 4;
    while (k > 1 && fixedBytes + 3ull * k * NN * HID * 4 > ws_size) k >>= 1;
    long K = (long)k * NN;           // rows per pass
    int npass = 4 / k;
    int gvPerXcd = (int)(K / 1024) / 8;   // graph-view chunks per XCD

    float* bufA = (float*)(wsb + off);            // [K][128]
    float* bufB = bufA + K * HID;                 // [K][128]
    float* bufC = bufB + K * HID;                 // [K][128]

    // --- CSR build (shared by all views/layers) ---
    hipMemsetAsync(ptrw, 0, NN * sizeof(int), stream);
    count_kernel<<<EE / 256, 256, 0, stream>>>(dst, ptrw);
    scan_kernel<<<1, 1024, 0, stream>>>(ptrw, ptr);
    scatter_kernel<<<EE / 256, 256, 0, stream>>>(src, dst, ptrw, csr);

    // --- emb = 0 ---
    hipMemsetAsync(emb, 0, (size_t)NN * HID * sizeof(float), stream);

    for (int p = 0; p < npass; p++) {
        int viewBase = p * k;
        // layer 0: hl->A, hr->B, hres->C;  attn0 (res=C) -> B (h0)
        l0_kernel<<<L0_BLOCKS, 256, 0, stream>>>(x, W0l, W0r, Wres0, bufA, bufB, bufC,
                                                 viewBase, K);
        attn_kernel<<<K / 4, 256, 0, stream>>>(bufA, bufB, bufC, ptr, csr, a0, bufB, 1, gvPerXcd);
        // layer 1: gemm B->(A=hl, C=hr);  attn1 (res=B) -> C (h1)
        gemm128<<<dim3(K / 128, 1, 2), 256, 0, stream>>>(bufB, Wl, Wr, bufA, bufC, nullptr, 0);
        attn_kernel<<<K / 4, 256, 0, stream>>>(bufA, bufC, bufB, ptr, csr, att, bufC, 1, gvPerXcd);
        // layer 2: gemm C->(A=hl, B=hr);  attn2 (res=C, no act) -> B (h2)
        gemm128<<<dim3(K / 128, 1, 2), 256, 0, stream>>>(bufC, Wl + HID * HID, Wr + HID * HID,
                                                         bufA, bufB, nullptr, 0);
        attn_kernel<<<K / 4, 256, 0, stream>>>(bufA, bufB, bufC, ptr, csr, att + HID, bufB, 0, gvPerXcd);
        // accumulate mean over views
        acc_kernel<<<NN * 32 / 256, 256, 0, stream>>>(bufB, emb, k);
    }

    // --- head: z = relu(emb@Wh1+bh1) -> bufA;  logits(bufA) -> out ---
    gemm128<<<dim3(NN / 128, 1, 1), 256, 0, stream>>>(emb, Wh1, Wh1, bufA, bufA, bh1, 1);
    logits_kernel<<<NN * 64 / 256, 256, 0, stream>>>(bufA, Wh2, bh2, out);
}

// Round 7
// 393.307 us; speedup vs baseline: 1.2434x; 1.1146x over previous
//
#include <hip/hip_runtime.h>
#include <hip/hip_bf16.h>
#include <math.h>

#define NN 16384       // nodes
#define EE 131072      // edges
#define FIN 16
#define HID 128
#define NEG_SLOPE 0.2f

typedef float  floatx4 __attribute__((ext_vector_type(4)));
typedef short  shortx8 __attribute__((ext_vector_type(8)));

// fp32 -> bf16 RNE split helpers (hi catches top 8 mantissa bits, lo the next 8)
__device__ inline unsigned bf_hi_bits(float x) {
    unsigned u = __float_as_uint(x);
    return (u + 0x7FFFu + ((u >> 16) & 1u)) >> 16;
}

// ---------------------------------------------------------------------------
// CSR build
// ---------------------------------------------------------------------------
__global__ void count_kernel(const int* __restrict__ dst, int* __restrict__ deg) {
    int e = blockIdx.x * 256 + threadIdx.x;
    atomicAdd(&deg[dst[e]], 1);
}

__global__ __launch_bounds__(1024) void scan_kernel(int* __restrict__ degw /* in: deg, out: offsets */,
                                                    int* __restrict__ ptr) {
    __shared__ int sums[1024];
    int t = threadIdx.x;
    int base = t * 16;
    int local[16];
    int s = 0;
#pragma unroll
    for (int i = 0; i < 16; i++) { local[i] = degw[base + i]; s += local[i]; }
    sums[t] = s;
    __syncthreads();
    for (int off = 1; off < 1024; off <<= 1) {
        int v = (t >= off) ? sums[t - off] : 0;
        __syncthreads();
        sums[t] += v;
        __syncthreads();
    }
    int ex = (t == 0) ? 0 : sums[t - 1];
#pragma unroll
    for (int i = 0; i < 16; i++) {
        ptr[base + i] = ex;
        degw[base + i] = ex;   // working copy for scatter
        ex += local[i];
    }
    if (t == 1023) ptr[NN] = sums[1023];
}

__global__ void scatter_kernel(const int* __restrict__ src, const int* __restrict__ dst,
                               int* __restrict__ ptrw, int* __restrict__ csr_src) {
    int e = blockIdx.x * 256 + threadIdx.x;
    int p = atomicAdd(&ptrw[dst[e]], 1);
    csr_src[p] = src[e];
}

// ---------------------------------------------------------------------------
// Weight pre-split into MFMA B-fragment layout, once per call.
// mat: 0=Wl[0], 1=Wr[0], 2=Wl[1], 3=Wr[1], 4=Wh1. For mfma_f32_16x16x32_bf16,
// B-frag: lane l supplies B[k=(l>>4)*8+j][col=l&15] for j=0..7. Stored so one
// lane's 8 bf16 are contiguous: idx = ((mat*32 + ct*4 + kt)*64 + l)*8 + j.
// ---------------------------------------------------------------------------
__global__ void wsplit_kernel(const float* __restrict__ Wl, const float* __restrict__ Wr,
                              const float* __restrict__ Wh1,
                              unsigned short* __restrict__ hi, unsigned short* __restrict__ lo) {
    int mat = blockIdx.y;
    const float* W = (mat == 0) ? Wl : (mat == 1) ? Wr : (mat == 2) ? Wl + HID * HID
                   : (mat == 3) ? Wr + HID * HID : Wh1;
    int ct = blockIdx.x;             // col tile 0..7
    int t = threadIdx.x;
    int kt = t >> 6, l = t & 63;
    long obase = (((long)mat * 32 + (ct * 4 + kt)) * 64 + l) * 8;
    int c = ct * 16 + (l & 15);
    int kbase = kt * 32 + ((l >> 4) << 3);
#pragma unroll
    for (int j = 0; j < 8; j++) {
        float x = W[(kbase + j) * HID + c];
        unsigned hb = bf_hi_bits(x);
        float r = x - __uint_as_float(hb << 16);
        unsigned lb = bf_hi_bits(r);
        hi[obase + j] = (unsigned short)hb;
        lo[obase + j] = (unsigned short)lb;
    }
}

// ---------------------------------------------------------------------------
// Layer 0 linear, persistent grid-stride (r5: per-block LDS staging was the
// bottleneck; weights now live in registers, 2 cols/thread).
// ---------------------------------------------------------------------------
#define L0_BLOCKS 2048
__global__ __launch_bounds__(256) void l0_kernel(const float* __restrict__ x,
                                                 const float* __restrict__ W0l,
                                                 const float* __restrict__ W0r,
                                                 const float* __restrict__ Wres,
                                                 float* __restrict__ hl,
                                                 float* __restrict__ hr,
                                                 float* __restrict__ hres,
                                                 int viewBase, long totalRows) {
    int tid = threadIdx.x;
    int c2 = (tid & 63) * 2;
    float2 wl2[FIN], wr2[FIN], ws2[FIN];
#pragma unroll
    for (int k = 0; k < FIN; k++) {
        wl2[k] = *(const float2*)(W0l + k * HID + c2);
        wr2[k] = *(const float2*)(W0r + k * HID + c2);
        ws2[k] = *(const float2*)(Wres + k * HID + c2);
    }
    for (long lw = (long)blockIdx.x * 4 + (tid >> 6); lw < totalRows;
         lw += (long)L0_BLOCKS * 4) {
        int v = viewBase + (int)(lw >> 14);            // absolute view
        int n = (int)(lw & (NN - 1));                  // node
        const float* xr = x + (long)n * FIN;
        float al0 = 0.f, al1 = 0.f, ar0 = 0.f, ar1 = 0.f, as0 = 0.f, as1 = 0.f;
#pragma unroll
        for (int k = 0; k < FIN; k++) {
            float xk = xr[k];                          // wave-uniform
            if (k == 0 && (v & 1)) xk = -xk;           // flip x for views 1,3
            if (k == 1 && (v & 2)) xk = -xk;           // flip y for views 2,3
            al0 += xk * wl2[k].x; al1 += xk * wl2[k].y;
            ar0 += xk * wr2[k].x; ar1 += xk * wr2[k].y;
            as0 += xk * ws2[k].x; as1 += xk * ws2[k].y;
        }
        long base = lw * HID + c2;
        *(float2*)(hl + base)   = make_float2(al0, al1);
        *(float2*)(hr + base)   = make_float2(ar0, ar1);
        *(float2*)(hres + base) = make_float2(as0, as1);
    }
}

// ---------------------------------------------------------------------------
// GATv2 edge attention + aggregate + residual + (optional) ELU.
// One wave per local row, XCD-swizzled (graph-view chunk pinned to one XCD
// so its 512 KB hl working set stays L2-resident). Online softmax over
// incoming edges (CSR by dst), 2-edge unrolled. hout may alias hr or res.
// ---------------------------------------------------------------------------
__global__ __launch_bounds__(256) void attn_kernel(const float* __restrict__ hl,
                                                   const float* __restrict__ hr,
                                                   const float* __restrict__ res,
                                                   const int* __restrict__ ptr,
                                                   const int* __restrict__ csr_src,
                                                   const float* __restrict__ avec,
                                                   float* __restrict__ hout,
                                                   int act,
                                                   int gvPerXcd) {
    int xcd = blockIdx.x & 7;
    int slot = blockIdx.x >> 3;
    int gv = xcd * gvPerXcd + (slot >> 8);
    int within = slot & 255;
    int gw = (gv << 10) + (within << 2) + (threadIdx.x >> 6);  // local row
    int l = threadIdx.x & 63;
    int n = gw & (NN - 1);
    int col = ((l >> 4) << 5) + ((l & 15) << 1);     // head*32 + pair*2
    long base = (long)gw * HID;
    float2 hr2 = *(const float2*)(hr + base + col);
    float2 a2 = *(const float2*)(avec + col);
    float m = -INFINITY, ssum = 0.f, acc0 = 0.f, acc1 = 0.f;
    int beg = ptr[n], end = ptr[n + 1];
    long vbase = (long)(gw >> 14) * NN * HID;
    int j = beg;
    for (; j + 1 < end; j += 2) {
        int sa = csr_src[j];
        int sb = csr_src[j + 1];
        float2 ha = *(const float2*)(hl + vbase + (long)sa * HID + col);
        float2 hb = *(const float2*)(hl + vbase + (long)sb * HID + col);
        float sa0 = ha.x + hr2.x, sa1 = ha.y + hr2.y;
        float sb0 = hb.x + hr2.x, sb1 = hb.y + hr2.y;
        float ta0 = sa0 > 0.f ? sa0 : NEG_SLOPE * sa0;
        float ta1 = sa1 > 0.f ? sa1 : NEG_SLOPE * sa1;
        float tb0 = sb0 > 0.f ? sb0 : NEG_SLOPE * sb0;
        float tb1 = sb1 > 0.f ? sb1 : NEG_SLOPE * sb1;
        float p1 = ta0 * a2.x + ta1 * a2.y;
        float p2 = tb0 * a2.x + tb1 * a2.y;
        p1 += __shfl_xor(p1, 1, 16);
        p2 += __shfl_xor(p2, 1, 16);
        p1 += __shfl_xor(p1, 2, 16);
        p2 += __shfl_xor(p2, 2, 16);
        p1 += __shfl_xor(p1, 4, 16);
        p2 += __shfl_xor(p2, 4, 16);
        p1 += __shfl_xor(p1, 8, 16);
        p2 += __shfl_xor(p2, 8, 16);
        float m12 = fmaxf(p1, p2);
        float w1 = __expf(p1 - m12);
        float w2 = __expf(p2 - m12);
        float mn = fmaxf(m, m12);
        float cold = __expf(m - mn);    // first iter: exp(-inf)=0
        float c12 = __expf(m12 - mn);
        ssum = ssum * cold + (w1 + w2) * c12;
        acc0 = acc0 * cold + (w1 * ha.x + w2 * hb.x) * c12;
        acc1 = acc1 * cold + (w1 * ha.y + w2 * hb.y) * c12;
        m = mn;
    }
    if (j < end) {
        int sa = csr_src[j];
        float2 ha = *(const float2*)(hl + vbase + (long)sa * HID + col);
        float s0 = ha.x + hr2.x, s1 = ha.y + hr2.y;
        float t0 = s0 > 0.f ? s0 : NEG_SLOPE * s0;
        float t1 = s1 > 0.f ? s1 : NEG_SLOPE * s1;
        float p = t0 * a2.x + t1 * a2.y;
        p += __shfl_xor(p, 1, 16);
        p += __shfl_xor(p, 2, 16);
        p += __shfl_xor(p, 4, 16);
        p += __shfl_xor(p, 8, 16);
        float mn = fmaxf(m, p);
        float cold = __expf(m - mn);
        float wnew = __expf(p - mn);
        ssum = ssum * cold + wnew;
        acc0 = acc0 * cold + wnew * ha.x;
        acc1 = acc1 * cold + wnew * ha.y;
        m = mn;
    }
    float inv = 1.f / (ssum + 1e-16f);   // deg==0 -> acc=0 -> out = res (matches ref)
    float2 r2 = *(const float2*)(res + base + col);
    float o0 = acc0 * inv + r2.x;
    float o1 = acc1 * inv + r2.y;
    if (act) {
        o0 = o0 > 0.f ? o0 : expm1f(o0);
        o1 = o1 > 0.f ? o1 : expm1f(o1);
    }
    *(float2*)(hout + base + col) = make_float2(o0, o1);
}

// ---------------------------------------------------------------------------
// MFMA GEMM: C[M][128] = A[M][128] @ W[128][128], W pre-split bf16 (hi,lo),
// A split in-register. 3-product split: Ah*Wh + Ah*Wl + Al*Wh (~17-bit
// effective mantissa, error ~1e-5 rel). LDS-free: A-frag (8 consecutive k of
// one row) loads straight from global as 2x float4; W-frags come pre-laid-out.
// Block = 128 rows x 128 cols, 4 waves in 2x2, each wave 64x64 = 16 acc tiles.
// blockIdx.z selects (mat0,C0) / (mat1,C1).
// ---------------------------------------------------------------------------
__global__ __launch_bounds__(256) void gemm_mfma(const float* __restrict__ A,
                                                 const unsigned short* __restrict__ whi,
                                                 const unsigned short* __restrict__ wlo,
                                                 int mat0, int mat1,
                                                 float* __restrict__ C0, float* __restrict__ C1,
                                                 const float* __restrict__ bias, int doRelu) {
    int mat = (blockIdx.z == 0) ? mat0 : mat1;
    float* C = (blockIdx.z == 0) ? C0 : C1;
    const unsigned short* bh = whi + (long)mat * 16384;
    const unsigned short* bl = wlo + (long)mat * 16384;
    int tid = threadIdx.x;
    int w = tid >> 6, l = tid & 63;
    int rh = w >> 1, ch = w & 1;          // wave's row-half / col-half
    long row0 = (long)blockIdx.x * 128 + rh * 64;
    int lr = l & 15;                      // A-frag row within tile
    int lk = (l >> 4) << 3;               // A-frag k offset
    floatx4 acc[4][4];
#pragma unroll
    for (int i = 0; i < 4; i++)
#pragma unroll
        for (int j = 0; j < 4; j++) acc[i][j] = (floatx4)0.f;

    for (int kt = 0; kt < 4; kt++) {
        shortx8 bhf[4], blf[4];
#pragma unroll
        for (int ctl = 0; ctl < 4; ctl++) {
            int ct = ch * 4 + ctl;
            long fi = ((long)(ct * 4 + kt) * 64 + l) * 8;
            bhf[ctl] = *(const shortx8*)(bh + fi);
            blf[ctl] = *(const shortx8*)(bl + fi);
        }
#pragma unroll
        for (int rt = 0; rt < 4; rt++) {
            const float* ap = A + (row0 + rt * 16 + lr) * HID + kt * 32 + lk;
            float4 x0 = *(const float4*)(ap);
            float4 x1 = *(const float4*)(ap + 4);
            float xs[8] = {x0.x, x0.y, x0.z, x0.w, x1.x, x1.y, x1.z, x1.w};
            shortx8 ah, al;
#pragma unroll
            for (int i = 0; i < 8; i++) {
                unsigned hb = bf_hi_bits(xs[i]);
                float r = xs[i] - __uint_as_float(hb << 16);
                unsigned lb = bf_hi_bits(r);
                ah[i] = (short)hb;
                al[i] = (short)lb;
            }
#pragma unroll
            for (int ctl = 0; ctl < 4; ctl++)
                acc[rt][ctl] = __builtin_amdgcn_mfma_f32_16x16x32_bf16(ah, bhf[ctl], acc[rt][ctl], 0, 0, 0);
#pragma unroll
            for (int ctl = 0; ctl < 4; ctl++)
                acc[rt][ctl] = __builtin_amdgcn_mfma_f32_16x16x32_bf16(ah, blf[ctl], acc[rt][ctl], 0, 0, 0);
#pragma unroll
            for (int ctl = 0; ctl < 4; ctl++)
                acc[rt][ctl] = __builtin_amdgcn_mfma_f32_16x16x32_bf16(al, bhf[ctl], acc[rt][ctl], 0, 0, 0);
        }
    }
    // epilogue: C/D layout col = lane&15, row = (lane>>4)*4 + reg  [m89-verified]
    int lrow4 = (l >> 4) * 4;
#pragma unroll
    for (int rt = 0; rt < 4; rt++) {
#pragma unroll
        for (int ctl = 0; ctl < 4; ctl++) {
            int col = ch * 64 + ctl * 16 + lr;
            float badd = bias ? bias[col] : 0.f;
#pragma unroll
            for (int rg = 0; rg < 4; rg++) {
                long row = row0 + rt * 16 + lrow4 + rg;
                float v = acc[rt][ctl][rg] + badd;
                if (doRelu) v = fmaxf(v, 0.f);
                C[row * HID + col] = v;
            }
        }
    }
}

// ---------------------------------------------------------------------------
// Accumulate 0.25 * sum over the pass's k views into emb  (emb pre-zeroed)
// ---------------------------------------------------------------------------
__global__ void acc_kernel(const float* __restrict__ h, float* __restrict__ emb, int k) {
    int i = blockIdx.x * 256 + threadIdx.x;  // over NN*32 float4s
    const float4* h4 = (const float4*)h;
    float4 s = make_float4(0.f, 0.f, 0.f, 0.f);
    for (int lv = 0; lv < k; lv++) {
        float4 a = h4[i + (long)lv * NN * 32];
        s.x += a.x; s.y += a.y; s.z += a.z; s.w += a.w;
    }
    float4* e4 = (float4*)emb;
    float4 o = e4[i];
    o.x += 0.25f * s.x; o.y += 0.25f * s.y; o.z += 0.25f * s.z; o.w += 0.25f * s.w;
    e4[i] = o;
}

// ---------------------------------------------------------------------------
// Final logits: out[n] = z[n][:] . Wh2 + bh2   (one wave per node)
// ---------------------------------------------------------------------------
__global__ void logits_kernel(const float* __restrict__ z, const float* __restrict__ Wh2,
                              const float* __restrict__ bh2, float* __restrict__ out) {
    int w = (blockIdx.x * 256 + threadIdx.x) >> 6;
    int l = threadIdx.x & 63;
    float v = z[(long)w * HID + l] * Wh2[l] + z[(long)w * HID + 64 + l] * Wh2[64 + l];
    v += __shfl_xor(v, 32);
    v += __shfl_xor(v, 16);
    v += __shfl_xor(v, 8);
    v += __shfl_xor(v, 4);
    v += __shfl_xor(v, 2);
    v += __shfl_xor(v, 1);
    if (l == 0) out[w] = v + bh2[0];
}

// ---------------------------------------------------------------------------
extern "C" void kernel_launch(void* const* d_in, const int* in_sizes, int n_in,
                              void* d_out, int out_size, void* d_ws, size_t ws_size,
                              hipStream_t stream) {
    const float* x    = (const float*)d_in[0];
    const int*   ei   = (const int*)d_in[1];      // [2][E]: src then dst
    const float* W0l  = (const float*)d_in[3];
    const float* W0r  = (const float*)d_in[4];
    const float* a0   = (const float*)d_in[5];
    const float* Wres0= (const float*)d_in[6];
    const float* Wl   = (const float*)d_in[7];    // [2][128][128]
    const float* Wr   = (const float*)d_in[8];
    const float* att  = (const float*)d_in[9];    // [2][4][32]
    const float* Wh1  = (const float*)d_in[10];
    const float* bh1  = (const float*)d_in[11];
    const float* Wh2  = (const float*)d_in[12];
    const float* bh2  = (const float*)d_in[13];
    float* out = (float*)d_out;

    const int* src = ei;
    const int* dst = ei + EE;

    // workspace: emb | ptr | ptrw | csr | whi | wlo | (256B-aligned) bufA | bufB | bufC
    char* wsb = (char*)d_ws;
    float* emb = (float*)wsb;                               // [NN][128]
    size_t off = (size_t)NN * HID * 4;
    int* ptr  = (int*)(wsb + off);  off += (NN + 1) * 4;    // [NN+1]
    int* ptrw = (int*)(wsb + off);  off += NN * 4;          // [NN]
    int* csr  = (int*)(wsb + off);  off += (size_t)EE * 4;  // [EE]
    off = (off + 255) & ~(size_t)255;
    unsigned short* whi = (unsigned short*)(wsb + off); off += 5 * 16384 * 2;  // 160 KB
    unsigned short* wlo = (unsigned short*)(wsb + off); off += 5 * 16384 * 2;  // 160 KB
    off = (off + 255) & ~(size_t)255;
    size_t fixedBytes = off;

    // ws-adaptive pass sizing: k views per pass, k in {4,2,1}
    int k = 4;
    while (k > 1 && fixedBytes + 3ull * k * NN * HID * 4 > ws_size) k >>= 1;
    long K = (long)k * NN;           // rows per pass
    int npass = 4 / k;
    int gvPerXcd = (int)(K / 1024) / 8;   // graph-view chunks per XCD

    float* bufA = (float*)(wsb + off);            // [K][128]
    float* bufB = bufA + K * HID;                 // [K][128]
    float* bufC = bufB + K * HID;                 // [K][128]

    // --- CSR build (shared by all views/layers) + weight split ---
    hipMemsetAsync(ptrw, 0, NN * sizeof(int), stream);
    count_kernel<<<EE / 256, 256, 0, stream>>>(dst, ptrw);
    scan_kernel<<<1, 1024, 0, stream>>>(ptrw, ptr);
    scatter_kernel<<<EE / 256, 256, 0, stream>>>(src, dst, ptrw, csr);
    wsplit_kernel<<<dim3(8, 5), 256, 0, stream>>>(Wl, Wr, Wh1, whi, wlo);

    // --- emb = 0 ---
    hipMemsetAsync(emb, 0, (size_t)NN * HID * sizeof(float), stream);

    for (int p = 0; p < npass; p++) {
        int viewBase = p * k;
        // layer 0: hl->A, hr->B, hres->C;  attn0 (res=C) -> B (h0)
        l0_kernel<<<L0_BLOCKS, 256, 0, stream>>>(x, W0l, W0r, Wres0, bufA, bufB, bufC,
                                                 viewBase, K);
        attn_kernel<<<K / 4, 256, 0, stream>>>(bufA, bufB, bufC, ptr, csr, a0, bufB, 1, gvPerXcd);
        // layer 1: gemm B->(A=hl via Wl0, C=hr via Wr0);  attn1 (res=B) -> C (h1)
        gemm_mfma<<<dim3(K / 128, 1, 2), 256, 0, stream>>>(bufB, whi, wlo, 0, 1,
                                                           bufA, bufC, nullptr, 0);
        attn_kernel<<<K / 4, 256, 0, stream>>>(bufA, bufC, bufB, ptr, csr, att, bufC, 1, gvPerXcd);
        // layer 2: gemm C->(A=hl via Wl1, B=hr via Wr1);  attn2 (res=C, no act) -> B (h2)
        gemm_mfma<<<dim3(K / 128, 1, 2), 256, 0, stream>>>(bufC, whi, wlo, 2, 3,
                                                           bufA, bufB, nullptr, 0);
        attn_kernel<<<K / 4, 256, 0, stream>>>(bufA, bufB, bufC, ptr, csr, att + HID, bufB, 0, gvPerXcd);
        // accumulate mean over views
        acc_kernel<<<NN * 32 / 256, 256, 0, stream>>>(bufB, emb, k);
    }

    // --- head: z = relu(emb@Wh1+bh1) -> bufA;  logits(bufA) -> out ---
    gemm_mfma<<<dim3(NN / 128, 1, 1), 256, 0, stream>>>(emb, whi, wlo, 4, 4,
                                                        bufA, bufA, bh1, 1);
    logits_kernel<<<NN * 64 / 256, 256, 0, stream>>>(bufA, Wh2, bh2, out);
}

// Round 8
// 361.544 us; speedup vs baseline: 1.3526x; 1.0879x over previous
//
#include <hip/hip_runtime.h>
#include <hip/hip_bf16.h>
#include <math.h>

#define NN 16384       // nodes
#define EE 131072      // edges
#define FIN 16
#define HID 128
#define NEG_SLOPE 0.2f

typedef float  floatx4 __attribute__((ext_vector_type(4)));
typedef short  shortx8 __attribute__((ext_vector_type(8)));

// fp32 -> bf16 RNE split helpers (hi catches top 8 mantissa bits, lo the next 8)
__device__ inline unsigned bf_hi_bits(float x) {
    unsigned u = __float_as_uint(x);
    return (u + 0x7FFFu + ((u >> 16) & 1u)) >> 16;
}

// ---------------------------------------------------------------------------
// CSR build
// ---------------------------------------------------------------------------
__global__ void count_kernel(const int* __restrict__ dst, int* __restrict__ deg) {
    int e = blockIdx.x * 256 + threadIdx.x;
    atomicAdd(&deg[dst[e]], 1);
}

__global__ __launch_bounds__(1024) void scan_kernel(int* __restrict__ degw /* in: deg, out: offsets */,
                                                    int* __restrict__ ptr) {
    __shared__ int sums[1024];
    int t = threadIdx.x;
    int base = t * 16;
    int local[16];
    int s = 0;
#pragma unroll
    for (int i = 0; i < 16; i++) { local[i] = degw[base + i]; s += local[i]; }
    sums[t] = s;
    __syncthreads();
    for (int off = 1; off < 1024; off <<= 1) {
        int v = (t >= off) ? sums[t - off] : 0;
        __syncthreads();
        sums[t] += v;
        __syncthreads();
    }
    int ex = (t == 0) ? 0 : sums[t - 1];
#pragma unroll
    for (int i = 0; i < 16; i++) {
        ptr[base + i] = ex;
        degw[base + i] = ex;   // working copy for scatter
        ex += local[i];
    }
    if (t == 1023) ptr[NN] = sums[1023];
}

__global__ void scatter_kernel(const int* __restrict__ src, const int* __restrict__ dst,
                               int* __restrict__ ptrw, int* __restrict__ csr_src) {
    int e = blockIdx.x * 256 + threadIdx.x;
    int p = atomicAdd(&ptrw[dst[e]], 1);
    csr_src[p] = src[e];
}

// ---------------------------------------------------------------------------
// Weight pre-split into MFMA B-fragment layout, once per call.
// mat: 0=Wl[0], 1=Wr[0], 2=Wl[1], 3=Wr[1], 4=Wh1. For mfma_f32_16x16x32_bf16,
// B-frag: lane l supplies B[k=(l>>4)*8+j][col=l&15] for j=0..7. Stored so one
// lane's 8 bf16 are contiguous: idx = ((mat*32 + ct*4 + kt)*64 + l)*8 + j.
// ---------------------------------------------------------------------------
__global__ void wsplit_kernel(const float* __restrict__ Wl, const float* __restrict__ Wr,
                              const float* __restrict__ Wh1,
                              unsigned short* __restrict__ hi, unsigned short* __restrict__ lo) {
    int mat = blockIdx.y;
    const float* W = (mat == 0) ? Wl : (mat == 1) ? Wr : (mat == 2) ? Wl + HID * HID
                   : (mat == 3) ? Wr + HID * HID : Wh1;
    int ct = blockIdx.x;             // col tile 0..7
    int t = threadIdx.x;
    int kt = t >> 6, l = t & 63;
    long obase = (((long)mat * 32 + (ct * 4 + kt)) * 64 + l) * 8;
    int c = ct * 16 + (l & 15);
    int kbase = kt * 32 + ((l >> 4) << 3);
#pragma unroll
    for (int j = 0; j < 8; j++) {
        float x = W[(kbase + j) * HID + c];
        unsigned hb = bf_hi_bits(x);
        float r = x - __uint_as_float(hb << 16);
        unsigned lb = bf_hi_bits(r);
        hi[obase + j] = (unsigned short)hb;
        lo[obase + j] = (unsigned short)lb;
    }
}

// ---------------------------------------------------------------------------
// Layer 0 linear, persistent grid-stride (r5: per-block LDS staging was the
// bottleneck; weights now live in registers, 2 cols/thread).
// ---------------------------------------------------------------------------
#define L0_BLOCKS 2048
__global__ __launch_bounds__(256) void l0_kernel(const float* __restrict__ x,
                                                 const float* __restrict__ W0l,
                                                 const float* __restrict__ W0r,
                                                 const float* __restrict__ Wres,
                                                 float* __restrict__ hl,
                                                 float* __restrict__ hr,
                                                 float* __restrict__ hres,
                                                 int viewBase, long totalRows) {
    int tid = threadIdx.x;
    int c2 = (tid & 63) * 2;
    float2 wl2[FIN], wr2[FIN], ws2[FIN];
#pragma unroll
    for (int k = 0; k < FIN; k++) {
        wl2[k] = *(const float2*)(W0l + k * HID + c2);
        wr2[k] = *(const float2*)(W0r + k * HID + c2);
        ws2[k] = *(const float2*)(Wres + k * HID + c2);
    }
    for (long lw = (long)blockIdx.x * 4 + (tid >> 6); lw < totalRows;
         lw += (long)L0_BLOCKS * 4) {
        int v = viewBase + (int)(lw >> 14);            // absolute view
        int n = (int)(lw & (NN - 1));                  // node
        const float* xr = x + (long)n * FIN;
        float al0 = 0.f, al1 = 0.f, ar0 = 0.f, ar1 = 0.f, as0 = 0.f, as1 = 0.f;
#pragma unroll
        for (int k = 0; k < FIN; k++) {
            float xk = xr[k];                          // wave-uniform
            if (k == 0 && (v & 1)) xk = -xk;           // flip x for views 1,3
            if (k == 1 && (v & 2)) xk = -xk;           // flip y for views 2,3
            al0 += xk * wl2[k].x; al1 += xk * wl2[k].y;
            ar0 += xk * wr2[k].x; ar1 += xk * wr2[k].y;
            as0 += xk * ws2[k].x; as1 += xk * ws2[k].y;
        }
        long base = lw * HID + c2;
        *(float2*)(hl + base)   = make_float2(al0, al1);
        *(float2*)(hr + base)   = make_float2(ar0, ar1);
        *(float2*)(hres + base) = make_float2(as0, as1);
    }
}

// ---------------------------------------------------------------------------
// GATv2 edge attention + aggregate + residual + (optional) ELU.
// r7 rework: attn was VALU-issue-bound (73% VALUBusy, 19% HBM). New layout:
// wave = 4 edge-slots x 16 lanes, 8 dims/lane. Each 16-lane group handles a
// full edge (2x dwordx4/lane); head-dot reduce = 2 shuffles over a 4-lane
// group (head = dims/32 = (l&15)>>2); 4 edges retire per iteration vs 2,
// at ~17 inst/edge vs ~27. Slots run independent online softmax over an
// interleaved quarter of the edge list; one cross-slot merge per node.
// XCD swizzle unchanged (graph-view chunk pinned to one XCD, L2-resident).
// hout may alias hr or res (row-local reads before the only write).
// ---------------------------------------------------------------------------
__global__ __launch_bounds__(256) void attn_kernel(const float* __restrict__ hl,
                                                   const float* __restrict__ hr,
                                                   const float* __restrict__ res,
                                                   const int* __restrict__ ptr,
                                                   const int* __restrict__ csr_src,
                                                   const float* __restrict__ avec,
                                                   float* __restrict__ hout,
                                                   int act,
                                                   int gvPerXcd) {
    int xcd = blockIdx.x & 7;
    int slotb = blockIdx.x >> 3;
    int gv = xcd * gvPerXcd + (slotb >> 8);
    int within = slotb & 255;
    int gw = (gv << 10) + (within << 2) + (threadIdx.x >> 6);  // local row
    int l = threadIdx.x & 63;
    int es = l >> 4;                 // edge slot 0..3
    int col = (l & 15) * 8;          // 8 dims per lane
    int n = gw & (NN - 1);
    long base = (long)gw * HID;
    const float* hrp = hr + base + col;
    float4 hrA = *(const float4*)(hrp);
    float4 hrB = *(const float4*)(hrp + 4);
    float4 aA = *(const float4*)(avec + col);
    float4 aB = *(const float4*)(avec + col + 4);
    float m = -INFINITY, ssum = 0.f;
    float4 acA = make_float4(0.f, 0.f, 0.f, 0.f);
    float4 acB = make_float4(0.f, 0.f, 0.f, 0.f);
    int beg = ptr[n], end = ptr[n + 1];
    const float* hlv = hl + (long)(gw >> 14) * NN * HID;   // view base in pass

    for (int j = beg + es; j < end; j += 4) {
        int sn = csr_src[j];                 // group-uniform (broadcast)
        const float* hp = hlv + ((sn << 7) + col);
        float4 hA = *(const float4*)(hp);
        float4 hB = *(const float4*)(hp + 4);
        // t = lrelu(h + hr) = max(s,0) + 0.2*min(s,0); p = dot(t, a) over 8 dims
        float p;
        {
            float s0 = hA.x + hrA.x, s1 = hA.y + hrA.y, s2 = hA.z + hrA.z, s3 = hA.w + hrA.w;
            float s4 = hB.x + hrB.x, s5 = hB.y + hrB.y, s6 = hB.z + hrB.z, s7 = hB.w + hrB.w;
            float t0 = fmaxf(s0, 0.f) + NEG_SLOPE * fminf(s0, 0.f);
            float t1 = fmaxf(s1, 0.f) + NEG_SLOPE * fminf(s1, 0.f);
            float t2 = fmaxf(s2, 0.f) + NEG_SLOPE * fminf(s2, 0.f);
            float t3 = fmaxf(s3, 0.f) + NEG_SLOPE * fminf(s3, 0.f);
            float t4 = fmaxf(s4, 0.f) + NEG_SLOPE * fminf(s4, 0.f);
            float t5 = fmaxf(s5, 0.f) + NEG_SLOPE * fminf(s5, 0.f);
            float t6 = fmaxf(s6, 0.f) + NEG_SLOPE * fminf(s6, 0.f);
            float t7 = fmaxf(s7, 0.f) + NEG_SLOPE * fminf(s7, 0.f);
            p = t0 * aA.x + t1 * aA.y + t2 * aA.z + t3 * aA.w
              + t4 * aB.x + t5 * aB.y + t6 * aB.z + t7 * aB.w;
        }
        // reduce over the 4-lane head group (head = (l&15)>>2)
        p += __shfl_xor(p, 1, 4);
        p += __shfl_xor(p, 2, 4);
        // online softmax update for this slot
        float mn = fmaxf(m, p);
        float cold = __expf(m - mn);         // first edge: exp(-inf)=0
        float w = __expf(p - mn);
        ssum = ssum * cold + w;
        acA.x = acA.x * cold + w * hA.x;
        acA.y = acA.y * cold + w * hA.y;
        acA.z = acA.z * cold + w * hA.z;
        acA.w = acA.w * cold + w * hA.w;
        acB.x = acB.x * cold + w * hB.x;
        acB.y = acB.y * cold + w * hB.y;
        acB.z = acB.z * cold + w * hB.z;
        acB.w = acB.w * cold + w * hB.w;
        m = mn;
    }

    // merge the 4 slots (lanes l, l^16, l^32 hold same dims, different slots)
    float mG = fmaxf(m, __shfl_xor(m, 16));
    mG = fmaxf(mG, __shfl_xor(mG, 32));
    float sc = (m > -INFINITY) ? __expf(m - mG) : 0.f;   // empty slot -> 0
    ssum *= sc;
    acA.x *= sc; acA.y *= sc; acA.z *= sc; acA.w *= sc;
    acB.x *= sc; acB.y *= sc; acB.z *= sc; acB.w *= sc;
    ssum += __shfl_xor(ssum, 16); ssum += __shfl_xor(ssum, 32);
    acA.x += __shfl_xor(acA.x, 16); acA.x += __shfl_xor(acA.x, 32);
    acA.y += __shfl_xor(acA.y, 16); acA.y += __shfl_xor(acA.y, 32);
    acA.z += __shfl_xor(acA.z, 16); acA.z += __shfl_xor(acA.z, 32);
    acA.w += __shfl_xor(acA.w, 16); acA.w += __shfl_xor(acA.w, 32);
    acB.x += __shfl_xor(acB.x, 16); acB.x += __shfl_xor(acB.x, 32);
    acB.y += __shfl_xor(acB.y, 16); acB.y += __shfl_xor(acB.y, 32);
    acB.z += __shfl_xor(acB.z, 16); acB.z += __shfl_xor(acB.z, 32);
    acB.w += __shfl_xor(acB.w, 16); acB.w += __shfl_xor(acB.w, 32);

    if (es == 0) {
        float inv = 1.f / (ssum + 1e-16f);   // deg==0 -> acc=0 -> out = res
        const float* rp = res + base + col;
        float4 rA = *(const float4*)(rp);
        float4 rB = *(const float4*)(rp + 4);
        float o[8];
        o[0] = acA.x * inv + rA.x; o[1] = acA.y * inv + rA.y;
        o[2] = acA.z * inv + rA.z; o[3] = acA.w * inv + rA.w;
        o[4] = acB.x * inv + rB.x; o[5] = acB.y * inv + rB.y;
        o[6] = acB.z * inv + rB.z; o[7] = acB.w * inv + rB.w;
        if (act) {
#pragma unroll
            for (int i = 0; i < 8; i++)
                o[i] = o[i] > 0.f ? o[i] : (__expf(o[i]) - 1.f);
        }
        float* op = hout + base + col;
        *(float4*)(op)     = make_float4(o[0], o[1], o[2], o[3]);
        *(float4*)(op + 4) = make_float4(o[4], o[5], o[6], o[7]);
    }
}

// ---------------------------------------------------------------------------
// MFMA GEMM: C[M][128] = A[M][128] @ W[128][128], W pre-split bf16 (hi,lo),
// A split in-register. 3-product split: Ah*Wh + Ah*Wl + Al*Wh (~17-bit
// effective mantissa). LDS-free: A-frag (8 consecutive k of one row) loads
// straight from global as 2x float4; W-frags come pre-laid-out.
// Block = 128 rows x 128 cols, 4 waves in 2x2, each wave 64x64 = 16 acc tiles.
// blockIdx.z selects (mat0,C0) / (mat1,C1).
// ---------------------------------------------------------------------------
__global__ __launch_bounds__(256) void gemm_mfma(const float* __restrict__ A,
                                                 const unsigned short* __restrict__ whi,
                                                 const unsigned short* __restrict__ wlo,
                                                 int mat0, int mat1,
                                                 float* __restrict__ C0, float* __restrict__ C1,
                                                 const float* __restrict__ bias, int doRelu) {
    int mat = (blockIdx.z == 0) ? mat0 : mat1;
    float* C = (blockIdx.z == 0) ? C0 : C1;
    const unsigned short* bh = whi + (long)mat * 16384;
    const unsigned short* bl = wlo + (long)mat * 16384;
    int tid = threadIdx.x;
    int w = tid >> 6, l = tid & 63;
    int rh = w >> 1, ch = w & 1;          // wave's row-half / col-half
    long row0 = (long)blockIdx.x * 128 + rh * 64;
    int lr = l & 15;                      // A-frag row within tile
    int lk = (l >> 4) << 3;               // A-frag k offset
    floatx4 acc[4][4];
#pragma unroll
    for (int i = 0; i < 4; i++)
#pragma unroll
        for (int j = 0; j < 4; j++) acc[i][j] = (floatx4)0.f;

    for (int kt = 0; kt < 4; kt++) {
        shortx8 bhf[4], blf[4];
#pragma unroll
        for (int ctl = 0; ctl < 4; ctl++) {
            int ct = ch * 4 + ctl;
            long fi = ((long)(ct * 4 + kt) * 64 + l) * 8;
            bhf[ctl] = *(const shortx8*)(bh + fi);
            blf[ctl] = *(const shortx8*)(bl + fi);
        }
#pragma unroll
        for (int rt = 0; rt < 4; rt++) {
            const float* ap = A + (row0 + rt * 16 + lr) * HID + kt * 32 + lk;
            float4 x0 = *(const float4*)(ap);
            float4 x1 = *(const float4*)(ap + 4);
            float xs[8] = {x0.x, x0.y, x0.z, x0.w, x1.x, x1.y, x1.z, x1.w};
            shortx8 ah, al;
#pragma unroll
            for (int i = 0; i < 8; i++) {
                unsigned hb = bf_hi_bits(xs[i]);
                float r = xs[i] - __uint_as_float(hb << 16);
                unsigned lb = bf_hi_bits(r);
                ah[i] = (short)hb;
                al[i] = (short)lb;
            }
#pragma unroll
            for (int ctl = 0; ctl < 4; ctl++)
                acc[rt][ctl] = __builtin_amdgcn_mfma_f32_16x16x32_bf16(ah, bhf[ctl], acc[rt][ctl], 0, 0, 0);
#pragma unroll
            for (int ctl = 0; ctl < 4; ctl++)
                acc[rt][ctl] = __builtin_amdgcn_mfma_f32_16x16x32_bf16(ah, blf[ctl], acc[rt][ctl], 0, 0, 0);
#pragma unroll
            for (int ctl = 0; ctl < 4; ctl++)
                acc[rt][ctl] = __builtin_amdgcn_mfma_f32_16x16x32_bf16(al, bhf[ctl], acc[rt][ctl], 0, 0, 0);
        }
    }
    // epilogue: C/D layout col = lane&15, row = (lane>>4)*4 + reg  [m89-verified]
    int lrow4 = (l >> 4) * 4;
#pragma unroll
    for (int rt = 0; rt < 4; rt++) {
#pragma unroll
        for (int ctl = 0; ctl < 4; ctl++) {
            int col = ch * 64 + ctl * 16 + lr;
            float badd = bias ? bias[col] : 0.f;
#pragma unroll
            for (int rg = 0; rg < 4; rg++) {
                long row = row0 + rt * 16 + lrow4 + rg;
                float v = acc[rt][ctl][rg] + badd;
                if (doRelu) v = fmaxf(v, 0.f);
                C[row * HID + col] = v;
            }
        }
    }
}

// ---------------------------------------------------------------------------
// Accumulate 0.25 * sum over the pass's k views into emb  (emb pre-zeroed)
// ---------------------------------------------------------------------------
__global__ void acc_kernel(const float* __restrict__ h, float* __restrict__ emb, int k) {
    int i = blockIdx.x * 256 + threadIdx.x;  // over NN*32 float4s
    const float4* h4 = (const float4*)h;
    float4 s = make_float4(0.f, 0.f, 0.f, 0.f);
    for (int lv = 0; lv < k; lv++) {
        float4 a = h4[i + (long)lv * NN * 32];
        s.x += a.x; s.y += a.y; s.z += a.z; s.w += a.w;
    }
    float4* e4 = (float4*)emb;
    float4 o = e4[i];
    o.x += 0.25f * s.x; o.y += 0.25f * s.y; o.z += 0.25f * s.z; o.w += 0.25f * s.w;
    e4[i] = o;
}

// ---------------------------------------------------------------------------
// Final logits: out[n] = z[n][:] . Wh2 + bh2   (one wave per node)
// ---------------------------------------------------------------------------
__global__ void logits_kernel(const float* __restrict__ z, const float* __restrict__ Wh2,
                              const float* __restrict__ bh2, float* __restrict__ out) {
    int w = (blockIdx.x * 256 + threadIdx.x) >> 6;
    int l = threadIdx.x & 63;
    float v = z[(long)w * HID + l] * Wh2[l] + z[(long)w * HID + 64 + l] * Wh2[64 + l];
    v += __shfl_xor(v, 32);
    v += __shfl_xor(v, 16);
    v += __shfl_xor(v, 8);
    v += __shfl_xor(v, 4);
    v += __shfl_xor(v, 2);
    v += __shfl_xor(v, 1);
    if (l == 0) out[w] = v + bh2[0];
}

// ---------------------------------------------------------------------------
extern "C" void kernel_launch(void* const* d_in, const int* in_sizes, int n_in,
                              void* d_out, int out_size, void* d_ws, size_t ws_size,
                              hipStream_t stream) {
    const float* x    = (const float*)d_in[0];
    const int*   ei   = (const int*)d_in[1];      // [2][E]: src then dst
    const float* W0l  = (const float*)d_in[3];
    const float* W0r  = (const float*)d_in[4];
    const float* a0   = (const float*)d_in[5];
    const float* Wres0= (const float*)d_in[6];
    const float* Wl   = (const float*)d_in[7];    // [2][128][128]
    const float* Wr   = (const float*)d_in[8];
    const float* att  = (const float*)d_in[9];    // [2][4][32]
    const float* Wh1  = (const float*)d_in[10];
    const float* bh1  = (const float*)d_in[11];
    const float* Wh2  = (const float*)d_in[12];
    const float* bh2  = (const float*)d_in[13];
    float* out = (float*)d_out;

    const int* src = ei;
    const int* dst = ei + EE;

    // workspace: emb | ptr | ptrw | csr | whi | wlo | (256B-aligned) bufA | bufB | bufC
    char* wsb = (char*)d_ws;
    float* emb = (float*)wsb;                               // [NN][128]
    size_t off = (size_t)NN * HID * 4;
    int* ptr  = (int*)(wsb + off);  off += (NN + 1) * 4;    // [NN+1]
    int* ptrw = (int*)(wsb + off);  off += NN * 4;          // [NN]
    int* csr  = (int*)(wsb + off);  off += (size_t)EE * 4;  // [EE]
    off = (off + 255) & ~(size_t)255;
    unsigned short* whi = (unsigned short*)(wsb + off); off += 5 * 16384 * 2;  // 160 KB
    unsigned short* wlo = (unsigned short*)(wsb + off); off += 5 * 16384 * 2;  // 160 KB
    off = (off + 255) & ~(size_t)255;
    size_t fixedBytes = off;

    // ws-adaptive pass sizing: k views per pass, k in {4,2,1}
    int k = 4;
    while (k > 1 && fixedBytes + 3ull * k * NN * HID * 4 > ws_size) k >>= 1;
    long K = (long)k * NN;           // rows per pass
    int npass = 4 / k;
    int gvPerXcd = (int)(K / 1024) / 8;   // graph-view chunks per XCD

    float* bufA = (float*)(wsb + off);            // [K][128]
    float* bufB = bufA + K * HID;                 // [K][128]
    float* bufC = bufB + K * HID;                 // [K][128]

    // --- CSR build (shared by all views/layers) + weight split ---
    hipMemsetAsync(ptrw, 0, NN * sizeof(int), stream);
    count_kernel<<<EE / 256, 256, 0, stream>>>(dst, ptrw);
    scan_kernel<<<1, 1024, 0, stream>>>(ptrw, ptr);
    scatter_kernel<<<EE / 256, 256, 0, stream>>>(src, dst, ptrw, csr);
    wsplit_kernel<<<dim3(8, 5), 256, 0, stream>>>(Wl, Wr, Wh1, whi, wlo);

    // --- emb = 0 ---
    hipMemsetAsync(emb, 0, (size_t)NN * HID * sizeof(float), stream);

    for (int p = 0; p < npass; p++) {
        int viewBase = p * k;
        // layer 0: hl->A, hr->B, hres->C;  attn0 (res=C) -> B (h0)
        l0_kernel<<<L0_BLOCKS, 256, 0, stream>>>(x, W0l, W0r, Wres0, bufA, bufB, bufC,
                                                 viewBase, K);
        attn_kernel<<<K / 4, 256, 0, stream>>>(bufA, bufB, bufC, ptr, csr, a0, bufB, 1, gvPerXcd);
        // layer 1: gemm B->(A=hl via Wl0, C=hr via Wr0);  attn1 (res=B) -> C (h1)
        gemm_mfma<<<dim3(K / 128, 1, 2), 256, 0, stream>>>(bufB, whi, wlo, 0, 1,
                                                           bufA, bufC, nullptr, 0);
        attn_kernel<<<K / 4, 256, 0, stream>>>(bufA, bufC, bufB, ptr, csr, att, bufC, 1, gvPerXcd);
        // layer 2: gemm C->(A=hl via Wl1, B=hr via Wr1);  attn2 (res=C, no act) -> B (h2)
        gemm_mfma<<<dim3(K / 128, 1, 2), 256, 0, stream>>>(bufC, whi, wlo, 2, 3,
                                                           bufA, bufB, nullptr, 0);
        attn_kernel<<<K / 4, 256, 0, stream>>>(bufA, bufB, bufC, ptr, csr, att + HID, bufB, 0, gvPerXcd);
        // accumulate mean over views
        acc_kernel<<<NN * 32 / 256, 256, 0, stream>>>(bufB, emb, k);
    }

    // --- head: z = relu(emb@Wh1+bh1) -> bufA;  logits(bufA) -> out ---
    gemm_mfma<<<dim3(NN / 128, 1, 1), 256, 0, stream>>>(emb, whi, wlo, 4, 4,
                                                        bufA, bufA, bh1, 1);
    logits_kernel<<<NN * 64 / 256, 256, 0, stream>>>(bufA, Wh2, bh2, out);
}